// Round 1
// baseline (483.662 us; speedup 1.0000x reference)
//
#include <hip/hip_runtime.h>
#include <hip/hip_bf16.h>

// SpeakerLoss: d[i] = ||vs_i - other_vs_i||^2 ; same-speaker keep d,
// different-speaker hinge max(L - d, 0); output = mean over B. L = 1.0.
//
// Layout strategy: 16 lanes per row (D=64 floats = 16 float4), one float4
// per lane -> wave reads 1 KiB contiguous per input array (fully coalesced).
// Grid-stride loop, register accumulation, block partials to d_ws, tiny
// second kernel for the final reduction (no atomics, deterministic).

#define BLOCKS   1024
#define THREADS  256
#define MARGIN_L 1.0f

__global__ __launch_bounds__(THREADS) void speaker_loss_partial(
    const int* __restrict__ s,
    const float4* __restrict__ vs4,
    const int* __restrict__ os,
    const float4* __restrict__ ovs4,
    float* __restrict__ partials,
    int B) {
    const int n4 = B * 16;  // total float4 elements per matrix (16e6 < 2^31)
    const int stride = gridDim.x * blockDim.x;
    int i = blockIdx.x * blockDim.x + threadIdx.x;
    const float mask = ((threadIdx.x & 15) == 0) ? 1.0f : 0.0f;

    float acc = 0.0f;
    for (; i < n4; i += stride) {
        const int row = i >> 4;
        float4 a = vs4[i];
        float4 b = ovs4[i];
        float dx = a.x - b.x;
        float dy = a.y - b.y;
        float dz = a.z - b.z;
        float dw = a.w - b.w;
        float p = dx * dx + dy * dy + dz * dz + dw * dw;
        // Butterfly sum within the 16-lane row group (wave64: masks 1..8
        // only exchange inside each aligned 16-lane group).
        p += __shfl_xor(p, 1);
        p += __shfl_xor(p, 2);
        p += __shfl_xor(p, 4);
        p += __shfl_xor(p, 8);
        // All 16 lanes now hold d(row); hinge, count once per row via mask.
        float v = (s[row] == os[row]) ? p : fmaxf(MARGIN_L - p, 0.0f);
        acc += v * mask;
    }

    // acc is nonzero only on lanes 0,16,32,48 of each wave.
    acc += __shfl_xor(acc, 16);
    acc += __shfl_xor(acc, 32);
    // lane 0 of each wave now holds the wave total.

    __shared__ float warp_sums[THREADS / 64];
    const int wave = threadIdx.x >> 6;
    if ((threadIdx.x & 63) == 0) warp_sums[wave] = acc;
    __syncthreads();

    if (threadIdx.x == 0) {
        float t = 0.0f;
#pragma unroll
        for (int w = 0; w < THREADS / 64; ++w) t += warp_sums[w];
        partials[blockIdx.x] = t;
    }
}

__global__ __launch_bounds__(THREADS) void speaker_loss_finalize(
    const float* __restrict__ partials, int n, float* __restrict__ out,
    float invB) {
    float acc = 0.0f;
    for (int i = threadIdx.x; i < n; i += blockDim.x) acc += partials[i];
#pragma unroll
    for (int m = 1; m < 64; m <<= 1) acc += __shfl_xor(acc, m);

    __shared__ float warp_sums[THREADS / 64];
    const int wave = threadIdx.x >> 6;
    if ((threadIdx.x & 63) == 0) warp_sums[wave] = acc;
    __syncthreads();

    if (threadIdx.x == 0) {
        float t = 0.0f;
#pragma unroll
        for (int w = 0; w < THREADS / 64; ++w) t += warp_sums[w];
        out[0] = t * invB;
    }
}

extern "C" void kernel_launch(void* const* d_in, const int* in_sizes, int n_in,
                              void* d_out, int out_size, void* d_ws, size_t ws_size,
                              hipStream_t stream) {
    const int*    s    = (const int*)d_in[0];
    const float4* vs4  = (const float4*)d_in[1];
    const int*    os   = (const int*)d_in[2];
    const float4* ovs4 = (const float4*)d_in[3];
    float* out = (float*)d_out;
    float* partials = (float*)d_ws;
    const int B = in_sizes[0];

    speaker_loss_partial<<<BLOCKS, THREADS, 0, stream>>>(s, vs4, os, ovs4,
                                                         partials, B);
    speaker_loss_finalize<<<1, THREADS, 0, stream>>>(partials, BLOCKS, out,
                                                     1.0f / (float)B);
}